// Round 7
// baseline (178.103 us; speedup 1.0000x reference)
//
#include <hip/hip_runtime.h>
#include <hip/hip_bf16.h>
#include <stdint.h>

typedef __attribute__((ext_vector_type(8))) __bf16 bf16x8;
typedef __attribute__((ext_vector_type(4))) __bf16 bf16x4;
typedef __attribute__((ext_vector_type(4))) float f32x4;

#define QSCALE (0.125f * 1.44269504f)

#define GL16(src, dst) __builtin_amdgcn_global_load_lds( \
    (const __attribute__((address_space(1))) void*)(src), \
    (__attribute__((address_space(3))) void*)(dst), 16, 0, 0)

static __device__ inline unsigned pkbf(float a, float b) {
  __bf16 x = (__bf16)a, y = (__bf16)b;
  unsigned short ux = __builtin_bit_cast(unsigned short, x);
  unsigned short uy = __builtin_bit_cast(unsigned short, y);
  return ((unsigned)uy << 16) | ux;
}

static __device__ inline float ex2(float x) {
#if __has_builtin(__builtin_amdgcn_exp2f)
  return __builtin_amdgcn_exp2f(x);
#else
  float r;
  asm("v_exp_f32 %0, %1" : "=v"(r) : "v"(x));
  return r;
#endif
}

// ---------------- fused prep: 4x transpose-convert + rope table ----------------
// (x cvt is now fused into the QKV GEMM's A-staging.) Block ranges:
//   [0,4096)      wq  [2048][2048] -> bf16 [2048][2048]^T
//   [4096,5120)   wk  [2048][512]  -> bf16 [512][2048]^T   (into wqkvT+2048*2048)
//   [5120,6144)   wv  [2048][512]  -> bf16 [512][2048]^T   (into wqkvT+2560*2048)
//   [6144,10240)  wo  [2048][2048] -> bf16 [2048][2048]^T
//   [10240,10496) rope cos/sin table [2048][32] f32
__global__ __launch_bounds__(256) void k_prep(const float* __restrict__ wq,
                                              const float* __restrict__ wk,
                                              const float* __restrict__ wv,
                                              const float* __restrict__ wo,
                                              __bf16* __restrict__ wqkvT,
                                              __bf16* __restrict__ woT,
                                              float* __restrict__ ct,
                                              float* __restrict__ st) {
  int bid = blockIdx.x, tid = threadIdx.x;
  if (bid >= 10240) {  // ---- rope table ----
    int i = (bid - 10240) * 256 + tid;
    int s = i >> 5, j = i & 31;
    float invf = powf(10000.0f, -(float)j / 32.0f);
    float fr = (float)s * invf;
    ct[i] = cosf(fr);
    st[i] = sinf(fr);
    return;
  }
  // ---- transpose-convert ----
  __shared__ float tile[32][33];
  const float* w;
  __bf16* wT;
  int N, r;
  if (bid < 4096)       { r = bid;         w = wq; wT = wqkvT;                        N = 2048; }
  else if (bid < 5120)  { r = bid - 4096;  w = wk; wT = wqkvT + (size_t)2048 * 2048;  N = 512; }
  else if (bid < 6144)  { r = bid - 5120;  w = wv; wT = wqkvT + (size_t)2560 * 2048;  N = 512; }
  else                  { r = bid - 6144;  w = wo; wT = woT;                          N = 2048; }
  int ntiles = N >> 5;
  int n0 = (r % ntiles) * 32, k0 = (r / ntiles) * 32;
  int tx = tid & 31, ty = tid >> 5;  // (32,8)
#pragma unroll
  for (int i = 0; i < 32; i += 8)
    tile[ty + i][tx] = w[(size_t)(k0 + ty + i) * N + n0 + tx];
  __syncthreads();
#pragma unroll
  for (int i = 0; i < 32; i += 8)
    wT[(size_t)(n0 + ty + i) * 2048 + k0 + tx] = (__bf16)tile[tx][ty + i];
}

// ---------------- QKV GEMM with fused f32->bf16 A-staging ----------------
// BM=256, BN=192, 12 waves (3Nx4M), grid 16x16=256 -> every CU gets one block.
// A is reg-staged from x (f32): loads for tile t+2 issued at tile-t START (pinned
// by sched_barrier so ~4200cy of flight), converted + ds_written (same swizzled
// layout) right after the mid barrier. B keeps global_load_lds, 2 tiles deep.
// Wait algebra (uniform across lanes): mid vmcnt(2) leaves only B(t+2) in flight
// => A(t+2) returned AND B(t+1) landed. ds_writes to lA[buf] start after the mid
// barrier (all readers done) and drain at the NEXT tile's mid lgkmcnt(0), one
// barrier before t+2's readers. No end-of-tile vmcnt needed.
__global__ __launch_bounds__(768, 3) void k_gemmqkv(const float* __restrict__ X,
                                                    const __bf16* __restrict__ BT,
                                                    __bf16* __restrict__ qb,
                                                    __bf16* __restrict__ kb,
                                                    __bf16* __restrict__ vt,
                                                    const float* __restrict__ ct,
                                                    const float* __restrict__ st,
                                                    int K, int NBN) {
  constexpr int BN = 192, WPN = 3;
  constexpr int MF = 4, NF = 4, MH = 2;   // 4 M-frags, 4 N-frags (64-col head window)
  constexpr int PB = BN * 8 / 768;        // 2 B gload_lds per thread per tile
  __shared__ __align__(16) __bf16 lA[2][256 * 64];
  __shared__ __align__(16) __bf16 lB[2][BN * 64];
  int bm = (blockIdx.x / NBN) << 8;
  int bn = (blockIdx.x % NBN) * BN;
  int tid = threadIdx.x, l = tid & 63, w = tid >> 6;
  int wr = w / WPN, wc = w % WPN;
  int lrow = l & 15, lk = l >> 4;
  int NT = K >> 6;
  f32x4 acc[MF][NF] = {};

  // A chunks: 2048 16B-chunks/tile over 768 threads -> 2 each + 1 extra for tid<512
  int ch0 = tid, ch1 = 768 + tid, ch2 = 1536 + tid;
  bool has2 = (tid < 512);   // wave-uniform (boundary at wave 8)

#define ALOAD(dst, ch, T)                                                     \
  do {                                                                        \
    const float4* p_ = (const float4*)(X + (size_t)(bm + ((ch) >> 3)) * K +   \
                                       ((T) << 6) +                           \
                                       ((((ch) & 7) ^ (((ch) >> 3) & 7)) << 3)); \
    (dst)[0] = p_[0];                                                         \
    (dst)[1] = p_[1];                                                         \
  } while (0)

#define ACVT(src, ch, BUF)                                                    \
  do {                                                                        \
    bf16x8 o_;                                                                \
    o_[0] = (__bf16)(src)[0].x; o_[1] = (__bf16)(src)[0].y;                   \
    o_[2] = (__bf16)(src)[0].z; o_[3] = (__bf16)(src)[0].w;                   \
    o_[4] = (__bf16)(src)[1].x; o_[5] = (__bf16)(src)[1].y;                   \
    o_[6] = (__bf16)(src)[1].z; o_[7] = (__bf16)(src)[1].w;                   \
    *(bf16x8*)((char*)lA[BUF] + (size_t)(ch) * 16) = o_;                      \
  } while (0)

#define STGB(T, BUF)                                                          \
  do {                                                                        \
    int k0_ = (T) << 6;                                                       \
    _Pragma("unroll") for (int i_ = 0; i_ < PB; i_++) {                       \
      int ch_ = i_ * 768 + tid;                                               \
      int r_ = ch_ >> 3, c_ = ch_ & 7;                                        \
      GL16(BT + (size_t)(bn + r_) * K + k0_ + ((c_ ^ (r_ & 7)) << 3),         \
           &lB[BUF][(i_ * 768 + (w << 6)) * 8]);                              \
    }                                                                         \
  } while (0)

  float4 p0[2], p1[2], p2[2];
  // ---- prologue ----
  ALOAD(p0, ch0, 0); ALOAD(p1, ch1, 0); if (has2) ALOAD(p2, ch2, 0);
  asm volatile("s_waitcnt vmcnt(0)" ::: "memory");
  ACVT(p0, ch0, 0); ACVT(p1, ch1, 0); if (has2) ACVT(p2, ch2, 0);
  ALOAD(p0, ch0, 1); ALOAD(p1, ch1, 1); if (has2) ALOAD(p2, ch2, 1);
  STGB(0, 0); STGB(1, 1);
  asm volatile("s_waitcnt vmcnt(4)" ::: "memory");   // A(1) returned; B0,B1 flying
  ACVT(p0, ch0, 1); ACVT(p1, ch1, 1); if (has2) ACVT(p2, ch2, 1);
  asm volatile("s_waitcnt vmcnt(2) lgkmcnt(0)" ::: "memory");  // B0 landed; writes drained
  __builtin_amdgcn_sched_barrier(0);
  __builtin_amdgcn_s_barrier();

  for (int t = 0; t < NT; t++) {
    int buf = t & 1;
    // issue A(t+2) f32 loads at tile start: ~1 full tile of flight
    if (t + 2 < NT) {
      ALOAD(p0, ch0, t + 2); ALOAD(p1, ch1, t + 2); if (has2) ALOAD(p2, ch2, t + 2);
      __builtin_amdgcn_sched_barrier(0);   // pin issue here (don't sink into the wait)
    }
    const char* bA = (const char*)lA[buf];
    const char* bB = (const char*)lB[buf];
    bf16x8 bfr[NF][2], af0[MH][2], af1[MH][2];
#pragma unroll
    for (int nf = 0; nf < NF; nf++) {
      int row = wc * (NF * 16) + nf * 16 + lrow;
#pragma unroll
      for (int kc = 0; kc < 2; kc++)
        bfr[nf][kc] = *(const bf16x8*)(bB + row * 128 +
                                       ((kc * 64 + 16 * lk) ^ ((row & 7) << 4)));
    }
#pragma unroll
    for (int mf = 0; mf < MH; mf++) {
      int row = wr * (MF * 16) + mf * 16 + lrow;
#pragma unroll
      for (int kc = 0; kc < 2; kc++)
        af0[mf][kc] = *(const bf16x8*)(bA + row * 128 +
                                       ((kc * 64 + 16 * lk) ^ ((row & 7) << 4)));
    }
    __builtin_amdgcn_s_setprio(1);
#pragma unroll
    for (int kc = 0; kc < 2; kc++)
#pragma unroll
      for (int mf = 0; mf < MH; mf++)
#pragma unroll
        for (int nf = 0; nf < NF; nf++)
          acc[mf][nf] = __builtin_amdgcn_mfma_f32_16x16x32_bf16(af0[mf][kc], bfr[nf][kc],
                                                                acc[mf][nf], 0, 0, 0);
    __builtin_amdgcn_s_setprio(0);
#pragma unroll
    for (int mf = 0; mf < MH; mf++) {
      int row = wr * (MF * 16) + (MH + mf) * 16 + lrow;
#pragma unroll
      for (int kc = 0; kc < 2; kc++)
        af1[mf][kc] = *(const bf16x8*)(bA + row * 128 +
                                       ((kc * 64 + 16 * lk) ^ ((row & 7) << 4)));
    }
    asm volatile("s_waitcnt lgkmcnt(0)" ::: "memory");
    __builtin_amdgcn_sched_barrier(0);
    __builtin_amdgcn_s_barrier();        // mid: all waves done reading buf
    if (t + 2 < NT) {
      STGB(t + 2, buf);                  // overwrite freed B buf
      asm volatile("s_waitcnt vmcnt(2)" ::: "memory");  // A(t+2) in regs; B(t+1) landed
      ACVT(p0, ch0, buf); ACVT(p1, ch1, buf); if (has2) ACVT(p2, ch2, buf);
    } else {
      asm volatile("s_waitcnt vmcnt(0)" ::: "memory");  // tail drain
    }
    __builtin_amdgcn_s_setprio(1);
#pragma unroll
    for (int kc = 0; kc < 2; kc++)
#pragma unroll
      for (int mf = 0; mf < MH; mf++)
#pragma unroll
        for (int nf = 0; nf < NF; nf++)
          acc[MH + mf][nf] = __builtin_amdgcn_mfma_f32_16x16x32_bf16(
              af1[mf][kc], bfr[nf][kc], acc[MH + mf][nf], 0, 0, 0);
    __builtin_amdgcn_s_setprio(0);
    __builtin_amdgcn_sched_barrier(0);
    __builtin_amdgcn_s_barrier();        // end
  }
#undef ALOAD
#undef ACVT
#undef STGB

  // fused QKV epilogue: RoPE Q/K, V transpose
  int wcb = bn + wc * 64;   // wave's 64-col window = one head
  if (wcb < 2048) {
#pragma unroll
    for (int mf = 0; mf < MF; mf++)
#pragma unroll
      for (int r = 0; r < 4; r++) {
        int row = bm + wr * (MF * 16) + mf * 16 + 4 * lk + r;
        int sidx = row & 2047;
#pragma unroll
        for (int nfl = 0; nfl < 2; nfl++) {
          int d = nfl * 16 + lrow;
          float c = ct[sidx * 32 + d], sn = st[sidx * 32 + d];
          float a = acc[mf][nfl][r], b2 = acc[mf][nfl + 2][r];
          qb[(size_t)row * 2048 + wcb + d] = (__bf16)((a * c - b2 * sn) * QSCALE);
          qb[(size_t)row * 2048 + wcb + d + 32] = (__bf16)((b2 * c + a * sn) * QSCALE);
        }
      }
  } else if (wcb < 2560) {
    int cb = wcb - 2048;
#pragma unroll
    for (int mf = 0; mf < MF; mf++)
#pragma unroll
      for (int r = 0; r < 4; r++) {
        int row = bm + wr * (MF * 16) + mf * 16 + 4 * lk + r;
        int sidx = row & 2047;
#pragma unroll
        for (int nfl = 0; nfl < 2; nfl++) {
          int d = nfl * 16 + lrow;
          float c = ct[sidx * 32 + d], sn = st[sidx * 32 + d];
          float a = acc[mf][nfl][r], b2 = acc[mf][nfl + 2][r];
          kb[(size_t)row * 512 + cb + d] = (__bf16)(a * c - b2 * sn);
          kb[(size_t)row * 512 + cb + d + 32] = (__bf16)(b2 * c + a * sn);
        }
      }
  } else {
    int hkk = (wcb - 2560) >> 6;
#pragma unroll
    for (int mf = 0; mf < MF; mf++)
#pragma unroll
      for (int nf = 0; nf < NF; nf++)
#pragma unroll
        for (int r = 0; r < 4; r++) {
          int row = bm + wr * (MF * 16) + mf * 16 + 4 * lk + r;
          int dd = nf * 16 + lrow;
          int bb = row >> 11, s = row & 2047;
          vt[(size_t)(((bb << 3) + hkk) * 64 + dd) * 2048 + s] = (__bf16)acc[mf][nf][r];
        }
  }
}

// ---------------- WO GEMM (round-2 measured-best): 3-deep A, upfront reads, swizzle ----
template <int BN, int NW, int WPN, int MODE>
__global__ __launch_bounds__(NW * 64, NW / 4) void k_gemm3d(const __bf16* __restrict__ A,
                                                            const __bf16* __restrict__ BT,
                                                            void* __restrict__ C0,
                                                            int K, int NBN) {
  constexpr int WPM = NW / WPN;
  constexpr int MF = 256 / WPM / 16;
  constexpr int NF = BN / WPN / 16;
  constexpr int MH = MF / 2;
  constexpr int CHA = 256 * 8;
  constexpr int CHB = BN * 8;
  constexpr int PA = CHA / (NW * 64);
  constexpr int RA = CHA - PA * NW * 64;
  constexpr int PB = CHB / (NW * 64);
  static_assert(CHB % (NW * 64) == 0, "B chunks must tile threads");
  static_assert(RA % 64 == 0, "A remainder must be wave-aligned");
  static_assert(NF == 4, "wave owns a 64-col window");
  constexpr int LB = PB;
  constexpr int LA0 = PA + (RA > 0 ? 1 : 0);
  constexpr int LA1 = PA;
  constexpr int NS0 = 2 * LA0 + LB, NS1 = 2 * LA1 + LB;
  constexpr int NM0 = LA0 + LB, NM1 = LA1 + LB;
  __shared__ __align__(16) __bf16 lA[3][256 * 64];
  __shared__ __align__(16) __bf16 lB[2][BN * 64];
  int bid = blockIdx.x;
  int lg = (bid & 7) * ((int)gridDim.x >> 3) + (bid >> 3);
  int bm = (lg / NBN) << 8;
  int bn = (lg % NBN) * BN;
  int tid = threadIdx.x, l = tid & 63, w = tid >> 6;
  int wr = w / WPN, wc = w % WPN;
  int lrow = l & 15, lk = l >> 4;
  int NT = K >> 6;
  f32x4 acc[MF][NF] = {};

#define STGA(T, BUF)                                                          \
  do {                                                                        \
    int k0_ = (T) << 6;                                                       \
    _Pragma("unroll") for (int i_ = 0; i_ < PA; i_++) {                       \
      int ch_ = i_ * (NW * 64) + tid;                                         \
      int r_ = ch_ >> 3, c_ = ch_ & 7;                                        \
      GL16(A + (size_t)(bm + r_) * K + k0_ + ((c_ ^ (r_ & 7)) << 3),          \
           &lA[BUF][(i_ * (NW * 64) + (w << 6)) * 8]);                        \
    }                                                                         \
    if constexpr (RA > 0) {                                                   \
      if (tid < RA) {                                                         \
        int ch_ = PA * (NW * 64) + tid;                                       \
        int r_ = ch_ >> 3, c_ = ch_ & 7;                                      \
        GL16(A + (size_t)(bm + r_) * K + k0_ + ((c_ ^ (r_ & 7)) << 3),        \
             &lA[BUF][(PA * (NW * 64) + (w << 6)) * 8]);                      \
      }                                                                       \
    }                                                                         \
  } while (0)

#define STGB(T, BUF)                                                          \
  do {                                                                        \
    int k0_ = (T) << 6;                                                       \
    _Pragma("unroll") for (int i_ = 0; i_ < PB; i_++) {                       \
      int ch_ = i_ * (NW * 64) + tid;                                         \
      int r_ = ch_ >> 3, c_ = ch_ & 7;                                        \
      GL16(BT + (size_t)(bn + r_) * K + k0_ + ((c_ ^ (r_ & 7)) << 3),         \
           &lB[BUF][(i_ * (NW * 64) + (w << 6)) * 8]);                        \
    }                                                                         \
  } while (0)

#define WAIT_STEADY()                                                         \
  do {                                                                        \
    if constexpr (RA > 0) {                                                   \
      if (w < (RA >> 6))                                                      \
        asm volatile("s_waitcnt vmcnt(%0)" ::"i"(NS0) : "memory");            \
      else                                                                    \
        asm volatile("s_waitcnt vmcnt(%0)" ::"i"(NS1) : "memory");            \
    } else {                                                                  \
      asm volatile("s_waitcnt vmcnt(%0)" ::"i"(NS1) : "memory");              \
    }                                                                         \
  } while (0)

#define WAIT_MID()                                                            \
  do {                                                                        \
    if constexpr (RA > 0) {                                                   \
      if (w < (RA >> 6))                                                      \
        asm volatile("s_waitcnt vmcnt(%0)" ::"i"(NM0) : "memory");            \
      else                                                                    \
        asm volatile("s_waitcnt vmcnt(%0)" ::"i"(NM1) : "memory");            \
    } else {                                                                  \
      asm volatile("s_waitcnt vmcnt(%0)" ::"i"(NM1) : "memory");              \
    }                                                                         \
  } while (0)

  STGB(0, 0); STGA(0, 0);
  STGB(1, 1); STGA(1, 1);
  STGA(2, 2);
  WAIT_STEADY();
  __builtin_amdgcn_sched_barrier(0);
  __builtin_amdgcn_s_barrier();

  int a0 = 0;
  for (int t = 0; t < NT; t++) {
    const char* bA = (const char*)lA[a0];
    const char* bB = (const char*)lB[t & 1];
    bf16x8 bfr[NF][2], af0[MH][2], af1[MH][2];
#pragma unroll
    for (int nf = 0; nf < NF; nf++) {
      int row = wc * (NF * 16) + nf * 16 + lrow;
#pragma unroll
      for (int kc = 0; kc < 2; kc++)
        bfr[nf][kc] = *(const bf16x8*)(bB + row * 128 +
                                       ((kc * 64 + 16 * lk) ^ ((row & 7) << 4)));
    }
#pragma unroll
    for (int mf = 0; mf < MH; mf++) {
      int row = wr * (MF * 16) + mf * 16 + lrow;
#pragma unroll
      for (int kc = 0; kc < 2; kc++)
        af0[mf][kc] = *(const bf16x8*)(bA + row * 128 +
                                       ((kc * 64 + 16 * lk) ^ ((row & 7) << 4)));
    }
#pragma unroll
    for (int mf = 0; mf < MH; mf++) {
      int row = wr * (MF * 16) + (MH + mf) * 16 + lrow;
#pragma unroll
      for (int kc = 0; kc < 2; kc++)
        af1[mf][kc] = *(const bf16x8*)(bA + row * 128 +
                                       ((kc * 64 + 16 * lk) ^ ((row & 7) << 4)));
    }
    __builtin_amdgcn_s_setprio(1);
#pragma unroll
    for (int kc = 0; kc < 2; kc++)
#pragma unroll
      for (int mf = 0; mf < MH; mf++)
#pragma unroll
        for (int nf = 0; nf < NF; nf++)
          acc[mf][nf] = __builtin_amdgcn_mfma_f32_16x16x32_bf16(af0[mf][kc], bfr[nf][kc],
                                                                acc[mf][nf], 0, 0, 0);
    __builtin_amdgcn_s_setprio(0);
    asm volatile("s_waitcnt lgkmcnt(0)" ::: "memory");
    __builtin_amdgcn_sched_barrier(0);
    __builtin_amdgcn_s_barrier();
    if (t + 2 < NT) STGB(t + 2, t & 1);
    if (t + 3 < NT) STGA(t + 3, a0);
    __builtin_amdgcn_s_setprio(1);
#pragma unroll
    for (int kc = 0; kc < 2; kc++)
#pragma unroll
      for (int mf = 0; mf < MH; mf++)
#pragma unroll
        for (int nf = 0; nf < NF; nf++)
          acc[MH + mf][nf] = __builtin_amdgcn_mfma_f32_16x16x32_bf16(
              af1[mf][kc], bfr[nf][kc], acc[MH + mf][nf], 0, 0, 0);
    __builtin_amdgcn_s_setprio(0);
    if (t + 3 < NT) {
      WAIT_STEADY();
    } else if (t + 2 < NT) {
      WAIT_MID();
    } else if (t + 1 < NT) {
      asm volatile("s_waitcnt vmcnt(0)" ::: "memory");
    }
    __builtin_amdgcn_sched_barrier(0);
    __builtin_amdgcn_s_barrier();
    a0 = (a0 == 2) ? 0 : a0 + 1;
  }
#undef STGA
#undef STGB
#undef WAIT_STEADY
#undef WAIT_MID

  float* C = (float*)C0;
#pragma unroll
  for (int mf = 0; mf < MF; mf++)
#pragma unroll
    for (int nf = 0; nf < NF; nf++)
#pragma unroll
      for (int r = 0; r < 4; r++) {
        int row = bm + wr * (MF * 16) + mf * 16 + 4 * lk + r;
        int col = bn + wc * 64 + nf * 16 + lrow;
        C[(size_t)row * 2048 + col] = acc[mf][nf][r];
      }
}

// ---------------- causal GQA flash attention v4c ----------------
// v4 structure (QBLK=32, grid 1024, descending-c dispatch — r5 measured-best),
// launch_bounds(256,3), setprio on MFMA clusters.
__global__ __launch_bounds__(256, 3) void k_attn(const __bf16* __restrict__ Q,
                                                 const __bf16* __restrict__ Kb,
                                                 const __bf16* __restrict__ VT,
                                                 __bf16* __restrict__ O) {
  __shared__ __align__(16) __bf16 lK[2][64 * 64];
  __shared__ __align__(16) __bf16 lV[2][64 * 64];
  int bid = blockIdx.x;            // 1024
  int c = 63 - (bid >> 4);         // q-chunk of 32 rows, most work first
  int hk = bid & 7;
  int b = (bid >> 3) & 1;
  int tid = threadIdx.x, l = tid & 63, w = tid >> 6;
  int h = hk * 4 + w;
  int lrow = l & 15, lk = l >> 4;
  int sw = (lrow & 7) << 4;
  int tl = c >> 1;                 // last kv tile index

#define STAGE(BUF, T)                                                                     \
  do {                                                                                    \
    int kv0_ = (T) * 64;                                                                  \
    _Pragma("unroll") for (int i_ = 0; i_ < 2; i_++) {                                    \
      int cb_ = i_ * 256 + w * 64;                                                        \
      int chunk_ = cb_ + l;                                                               \
      int row_ = chunk_ >> 3, cc_ = chunk_ & 7;                                           \
      GL16(Kb + (size_t)(b * 2048 + kv0_ + row_) * 512 + hk * 64 +                        \
               ((cc_ ^ (row_ & 7)) << 3),                                                 \
           &lK[BUF][cb_ * 8]);                                                            \
      GL16(VT + (size_t)((b * 8 + hk) * 64 + row_) * 2048 + kv0_ +                        \
               ((cc_ ^ (row_ & 7)) << 3),                                                 \
           &lV[BUF][cb_ * 8]);                                                            \
    }                                                                                     \
  } while (0)

  // Q fragments: 2 q-frags x 2 k-chunks, live in registers for the whole pass
  bf16x8 aq[2][2];
#pragma unroll
  for (int qf = 0; qf < 2; qf++) {
    int qrow = c * 32 + qf * 16 + lrow;
    const __bf16* qp = Q + (size_t)(b * 2048 + qrow) * 2048 + h * 64 + lk * 8;
    aq[qf][0] = *(const bf16x8*)qp;
    aq[qf][1] = *(const bf16x8*)(qp + 32);
  }
  f32x4 o[2][4] = {};
  float lp[2] = {0.f, 0.f};
  STAGE(0, 0);
  for (int t = 0, buf = 0; t <= tl; t++, buf ^= 1) {
    asm volatile("s_waitcnt vmcnt(0)" ::: "memory");
    __syncthreads();
    if (t < tl) STAGE(buf ^ 1, t + 1);
    const char* K_ = (const char*)lK[buf];
    const char* V_ = (const char*)lV[buf];
    // swapped QK^T: s4[qf][nf][r] = P^T[kv = nf*16+4*lk+r][q = lrow] (tile-local)
    f32x4 s4[2][4];
    __builtin_amdgcn_s_setprio(1);
#pragma unroll
    for (int nf = 0; nf < 4; nf++) {
      const char* kr = K_ + (nf * 16 + lrow) * 128;
      bf16x8 bk0 = *(const bf16x8*)(kr + ((16 * lk) ^ sw));
      bf16x8 bk1 = *(const bf16x8*)(kr + ((64 + 16 * lk) ^ sw));
#pragma unroll
      for (int qf = 0; qf < 2; qf++) {
        f32x4 z = {};
        z = __builtin_amdgcn_mfma_f32_16x16x32_bf16(bk0, aq[qf][0], z, 0, 0, 0);
        z = __builtin_amdgcn_mfma_f32_16x16x32_bf16(bk1, aq[qf][1], z, 0, 0, 0);
        s4[qf][nf] = z;
      }
    }
    __builtin_amdgcn_s_setprio(0);
    if (t == tl) {
      int qo = (c & 1) * 32;
#pragma unroll
      for (int qf = 0; qf < 2; qf++) {
        int qoff = qo + qf * 16 + lrow;
#pragma unroll
        for (int nf = 0; nf < 4; nf++)
#pragma unroll
          for (int r = 0; r < 4; r++)
            if (nf * 16 + 4 * lk + r > qoff) s4[qf][nf][r] = -1e30f;
      }
    }
    // no-max softmax: p = 2^s (s pre-scaled by log2e/8; bounded), in-lane partial sums
#pragma unroll
    for (int qf = 0; qf < 2; qf++) {
      float ps = 0.f;
#pragma unroll
      for (int nf = 0; nf < 4; nf++)
#pragma unroll
        for (int r = 0; r < 4; r++) {
          float pv = ex2(s4[qf][nf][r]);
          s4[qf][nf][r] = pv;
          ps += pv;
        }
      lp[qf] += ps;
    }
    // PV: o^T[d][q] += V^T * P^T, nf-tiles paired {np, np+2} into one 16x16x32 MFMA
    __builtin_amdgcn_s_setprio(1);
#pragma unroll
    for (int np = 0; np < 2; np++) {
      bf16x8 pb[2];
#pragma unroll
      for (int qf = 0; qf < 2; qf++) {
        uint4 t4;
        t4.x = pkbf(s4[qf][np][0], s4[qf][np][1]);
        t4.y = pkbf(s4[qf][np][2], s4[qf][np][3]);
        t4.z = pkbf(s4[qf][np + 2][0], s4[qf][np + 2][1]);
        t4.w = pkbf(s4[qf][np + 2][2], s4[qf][np + 2][3]);
        pb[qf] = __builtin_bit_cast(bf16x8, t4);
      }
#pragma unroll
      for (int dn = 0; dn < 4; dn++) {
        const char* vr = V_ + (dn * 16 + lrow) * 128;
        uint2 a0 = *(const uint2*)(vr + ((np * 32 + 8 * lk) ^ sw));
        uint2 a1 = *(const uint2*)(vr + (((np + 2) * 32 + 8 * lk) ^ sw));
        uint4 av;
        av.x = a0.x; av.y = a0.y; av.z = a1.x; av.w = a1.y;
        bf16x8 va = __builtin_bit_cast(bf16x8, av);
#pragma unroll
        for (int qf = 0; qf < 2; qf++)
          o[qf][dn] = __builtin_amdgcn_mfma_f32_16x16x32_bf16(va, pb[qf], o[qf][dn], 0, 0, 0);
      }
    }
    __builtin_amdgcn_s_setprio(0);
  }
  // epilogue: reduce lp across the 4 lk-lanes of each q-row, normalize, store b64 packs
#pragma unroll
  for (int qf = 0; qf < 2; qf++) {
    float s = lp[qf];
    s += __shfl_xor(s, 16);
    s += __shfl_xor(s, 32);
    float inv = 1.f / s;
    int qrow = c * 32 + qf * 16 + lrow;
    __bf16* op = O + (size_t)(b * 2048 + qrow) * 2048 + h * 64 + 4 * lk;
#pragma unroll
    for (int dn = 0; dn < 4; dn++) {
      bf16x4 stv;
#pragma unroll
      for (int r = 0; r < 4; r++) stv[r] = (__bf16)(o[qf][dn][r] * inv);
      *(bf16x4*)(op + dn * 16) = stv;
    }
  }
#undef STAGE
}

extern "C" void kernel_launch(void* const* d_in, const int* in_sizes, int n_in,
                              void* d_out, int out_size, void* d_ws, size_t ws_size,
                              hipStream_t stream) {
  const float* x = (const float*)d_in[0];
  const float* wq = (const float*)d_in[1];
  const float* wk = (const float*)d_in[2];
  const float* wv = (const float*)d_in[3];
  const float* wo = (const float*)d_in[4];
  char* ws = (char*)d_ws;
  __bf16* wqkvT = (__bf16*)(ws + 16777216);   // 12,582,912  [3072][2048]
  __bf16* woT   = (__bf16*)(ws + 29360128);   //  8,388,608
  __bf16* qb    = (__bf16*)(ws + 37748736);   // 16,777,216
  __bf16* kb    = (__bf16*)(ws + 54525952);   //  4,194,304
  __bf16* vt    = (__bf16*)(ws + 58720256);   //  4,194,304
  __bf16* ob    = (__bf16*)(ws + 62914560);   // 16,777,216
  float*  ct    = (float*)(ws + 79691776);    //    262,144
  float*  st    = (float*)(ws + 79953920);    //    262,144
  float* out = (float*)d_out;

  // fused prep: wq/wk/wv/wo transpose-convert + rope table (x cvt fused into QKV)
  k_prep<<<10496, 256, 0, stream>>>(wq, wk, wv, wo, wqkvT, woT, ct, st);
  // QKV: reads x (f32) directly, converts during A-staging.
  k_gemmqkv<<<256, 768, 0, stream>>>(x, wqkvT, qb, kb, vt, ct, st, 2048, 16);
  k_attn<<<1024, 256, 0, stream>>>(qb, kb, vt, ob);
  // WO: round-2 structure (3-deep A pipeline + XCD swizzle), measured faster for MODE 1.
  k_gemm3d<128, 8, 2, 1><<<256, 512, 0, stream>>>(ob, woT, out, 2048, 16);
}

// Round 8
// 160.499 us; speedup vs baseline: 1.1097x; 1.1097x over previous
//
#include <hip/hip_runtime.h>
#include <hip/hip_bf16.h>
#include <stdint.h>

typedef __attribute__((ext_vector_type(8))) __bf16 bf16x8;
typedef __attribute__((ext_vector_type(4))) __bf16 bf16x4;
typedef __attribute__((ext_vector_type(4))) float f32x4;

#define QSCALE (0.125f * 1.44269504f)

#define GL16(src, dst) __builtin_amdgcn_global_load_lds( \
    (const __attribute__((address_space(1))) void*)(src), \
    (__attribute__((address_space(3))) void*)(dst), 16, 0, 0)

static __device__ inline unsigned pkbf(float a, float b) {
  __bf16 x = (__bf16)a, y = (__bf16)b;
  unsigned short ux = __builtin_bit_cast(unsigned short, x);
  unsigned short uy = __builtin_bit_cast(unsigned short, y);
  return ((unsigned)uy << 16) | ux;
}

static __device__ inline float ex2(float x) {
#if __has_builtin(__builtin_amdgcn_exp2f)
  return __builtin_amdgcn_exp2f(x);
#else
  float r;
  asm("v_exp_f32 %0, %1" : "=v"(r) : "v"(x));
  return r;
#endif
}

// ---------------- fused prep: cvt + 4x transpose-convert + rope table ----------------
// One launch replaces six (r6 measured-best). Block ranges (all block-uniform):
//   [0,4096)      f32->bf16 cvt of x
//   [4096,8192)   wq  [2048][2048] -> bf16 [2048][2048]^T
//   [8192,9216)   wk  [2048][512]  -> bf16 [512][2048]^T   (into wqkvT+2048*2048)
//   [9216,10240)  wv  [2048][512]  -> bf16 [512][2048]^T   (into wqkvT+2560*2048)
//   [10240,14336) wo  [2048][2048] -> bf16 [2048][2048]^T
//   [14336,14592) rope cos/sin table [2048][32] f32
__global__ __launch_bounds__(256) void k_prep(const float* __restrict__ x,
                                              __bf16* __restrict__ xb,
                                              const float* __restrict__ wq,
                                              const float* __restrict__ wk,
                                              const float* __restrict__ wv,
                                              const float* __restrict__ wo,
                                              __bf16* __restrict__ wqkvT,
                                              __bf16* __restrict__ woT,
                                              float* __restrict__ ct,
                                              float* __restrict__ st) {
  int bid = blockIdx.x, tid = threadIdx.x;
  if (bid < 4096) {  // ---- cvt ----
    int i = bid * 256 + tid;
    const float4* p = (const float4*)(x) + (size_t)i * 2;
    float4 a = p[0], b = p[1];
    bf16x8 o;
    o[0] = (__bf16)a.x; o[1] = (__bf16)a.y; o[2] = (__bf16)a.z; o[3] = (__bf16)a.w;
    o[4] = (__bf16)b.x; o[5] = (__bf16)b.y; o[6] = (__bf16)b.z; o[7] = (__bf16)b.w;
    ((bf16x8*)xb)[i] = o;
    return;
  }
  if (bid >= 14336) {  // ---- rope table ----
    int i = (bid - 14336) * 256 + tid;
    int s = i >> 5, j = i & 31;
    float invf = powf(10000.0f, -(float)j / 32.0f);
    float fr = (float)s * invf;
    ct[i] = cosf(fr);
    st[i] = sinf(fr);
    return;
  }
  // ---- transpose-convert ----
  __shared__ float tile[32][33];
  const float* w;
  __bf16* wT;
  int N, r;
  if (bid < 8192)       { r = bid - 4096;  w = wq; wT = wqkvT;                        N = 2048; }
  else if (bid < 9216)  { r = bid - 8192;  w = wk; wT = wqkvT + (size_t)2048 * 2048;  N = 512; }
  else if (bid < 10240) { r = bid - 9216;  w = wv; wT = wqkvT + (size_t)2560 * 2048;  N = 512; }
  else                  { r = bid - 10240; w = wo; wT = woT;                          N = 2048; }
  int ntiles = N >> 5;
  int n0 = (r % ntiles) * 32, k0 = (r / ntiles) * 32;
  int tx = tid & 31, ty = tid >> 5;  // (32,8)
#pragma unroll
  for (int i = 0; i < 32; i += 8)
    tile[ty + i][tx] = w[(size_t)(k0 + ty + i) * N + n0 + tx];
  __syncthreads();
#pragma unroll
  for (int i = 0; i < 32; i += 8)
    wT[(size_t)(n0 + ty + i) * 2048 + k0 + tx] = (__bf16)tile[tx][ty + i];
}

// ---------------- QKV GEMM (round-1 measured-best): 2-deep, deferred af1 ----------------
// BM=256, NW waves, double-buffered LDS, staging 2 K-tiles ahead with counted vmcnt
// (never 0 mid-loop), raw s_barrier (no full drains), setprio on MFMA.
// MODE 0: BN=192, 12 waves (3Nx4M, 64-col head window/wave), grid 16x16=256 -> all CUs.
template <int BN, int NW, int WPN, int MODE>
__global__ __launch_bounds__(NW * 64, NW / 4) void k_gemm256(const __bf16* __restrict__ A,
                                                             const __bf16* __restrict__ BT,
                                                             void* __restrict__ C0,
                                                             __bf16* __restrict__ kb,
                                                             __bf16* __restrict__ vt,
                                                             const float* __restrict__ ct,
                                                             const float* __restrict__ st,
                                                             int K, int NBN) {
  constexpr int WPM = NW / WPN;         // waves along M
  constexpr int MF = 256 / WPM / 16;    // M-frags per wave
  constexpr int NF = BN / WPN / 16;     // N-frags per wave (64 cols)
  constexpr int MH = MF / 2;
  constexpr int CHA = 256 * 8;          // A 16B-chunks per K-tile
  constexpr int CHB = BN * 8;           // B 16B-chunks per K-tile
  constexpr int PA = CHA / (NW * 64);   // full A staging passes
  constexpr int RA = CHA - PA * NW * 64;// A remainder chunks (wave-aligned)
  constexpr int PB = CHB / (NW * 64);   // full B staging passes
  static_assert(CHB % (NW * 64) == 0, "B chunks must tile threads");
  static_assert(RA % 64 == 0, "A remainder must be wave-aligned");
  static_assert(NF == 4, "epilogue assumes 64-col wave window");
  __shared__ __align__(16) __bf16 lA[2][256 * 64];
  __shared__ __align__(16) __bf16 lB[2][BN * 64];
  int bm = (blockIdx.x / NBN) << 8;
  int bn = (blockIdx.x % NBN) * BN;
  int tid = threadIdx.x, l = tid & 63, w = tid >> 6;
  int wr = w / WPN, wc = w % WPN;
  int lrow = l & 15, lk = l >> 4;
  int NT = K >> 6;
  f32x4 acc[MF][NF] = {};

#define STG(T, BUF)                                                           \
  do {                                                                        \
    int k0_ = (T) << 6;                                                       \
    _Pragma("unroll") for (int i_ = 0; i_ < PA; i_++) {                       \
      int ch_ = i_ * (NW * 64) + tid;                                         \
      int r_ = ch_ >> 3, c_ = ch_ & 7;                                        \
      GL16(A + (size_t)(bm + r_) * K + k0_ + ((c_ ^ (r_ & 7)) << 3),          \
           &lA[BUF][(i_ * (NW * 64) + (w << 6)) * 8]);                        \
    }                                                                         \
    if constexpr (RA > 0) {                                                   \
      if (tid < RA) {                                                         \
        int ch_ = PA * (NW * 64) + tid;                                       \
        int r_ = ch_ >> 3, c_ = ch_ & 7;                                      \
        GL16(A + (size_t)(bm + r_) * K + k0_ + ((c_ ^ (r_ & 7)) << 3),        \
             &lA[BUF][(PA * (NW * 64) + (w << 6)) * 8]);                      \
      }                                                                       \
    }                                                                         \
    _Pragma("unroll") for (int i_ = 0; i_ < PB; i_++) {                       \
      int ch_ = i_ * (NW * 64) + tid;                                         \
      int r_ = ch_ >> 3, c_ = ch_ & 7;                                        \
      GL16(BT + (size_t)(bn + r_) * K + k0_ + ((c_ ^ (r_ & 7)) << 3),         \
           &lB[BUF][(i_ * (NW * 64) + (w << 6)) * 8]);                        \
    }                                                                         \
  } while (0)

#define WAITN()                                                               \
  do {                                                                        \
    if constexpr (RA > 0) {                                                   \
      if (w < (RA >> 6))                                                      \
        asm volatile("s_waitcnt vmcnt(%0)" ::"i"(PA + PB + 1) : "memory");    \
      else                                                                    \
        asm volatile("s_waitcnt vmcnt(%0)" ::"i"(PA + PB) : "memory");        \
    } else {                                                                  \
      asm volatile("s_waitcnt vmcnt(%0)" ::"i"(PA + PB) : "memory");          \
    }                                                                         \
  } while (0)

  STG(0, 0);
  STG(1, 1);
  WAITN();
  __builtin_amdgcn_sched_barrier(0);
  __builtin_amdgcn_s_barrier();

  for (int t = 0; t < NT; t++) {
    int buf = t & 1;
    const char* bA = (const char*)lA[buf];
    const char* bB = (const char*)lB[buf];
    bf16x8 bfr[NF][2], af0[MH][2], af1[MH][2];
#pragma unroll
    for (int nf = 0; nf < NF; nf++) {
      int row = wc * (NF * 16) + nf * 16 + lrow;
#pragma unroll
      for (int kc = 0; kc < 2; kc++)
        bfr[nf][kc] = *(const bf16x8*)(bB + row * 128 +
                                       ((kc * 64 + 16 * lk) ^ ((row & 7) << 4)));
    }
#pragma unroll
    for (int mf = 0; mf < MH; mf++) {
      int row = wr * (MF * 16) + mf * 16 + lrow;
#pragma unroll
      for (int kc = 0; kc < 2; kc++)
        af0[mf][kc] = *(const bf16x8*)(bA + row * 128 +
                                       ((kc * 64 + 16 * lk) ^ ((row & 7) << 4)));
    }
    __builtin_amdgcn_s_setprio(1);
#pragma unroll
    for (int kc = 0; kc < 2; kc++)
#pragma unroll
      for (int mf = 0; mf < MH; mf++)
#pragma unroll
        for (int nf = 0; nf < NF; nf++)
          acc[mf][nf] = __builtin_amdgcn_mfma_f32_16x16x32_bf16(af0[mf][kc], bfr[nf][kc],
                                                                acc[mf][nf], 0, 0, 0);
    __builtin_amdgcn_s_setprio(0);
#pragma unroll
    for (int mf = 0; mf < MH; mf++) {
      int row = wr * (MF * 16) + (MH + mf) * 16 + lrow;
#pragma unroll
      for (int kc = 0; kc < 2; kc++)
        af1[mf][kc] = *(const bf16x8*)(bA + row * 128 +
                                       ((kc * 64 + 16 * lk) ^ ((row & 7) << 4)));
    }
    asm volatile("s_waitcnt lgkmcnt(0)" ::: "memory");
    __builtin_amdgcn_sched_barrier(0);
    __builtin_amdgcn_s_barrier();        // all waves done reading buf
    if (t + 2 < NT) STG(t + 2, buf);     // overwrite freed buf, loads fly over MFMA
    __builtin_amdgcn_s_setprio(1);
#pragma unroll
    for (int kc = 0; kc < 2; kc++)
#pragma unroll
      for (int mf = 0; mf < MH; mf++)
#pragma unroll
        for (int nf = 0; nf < NF; nf++)
          acc[MH + mf][nf] = __builtin_amdgcn_mfma_f32_16x16x32_bf16(
              af1[mf][kc], bfr[nf][kc], acc[MH + mf][nf], 0, 0, 0);
    __builtin_amdgcn_s_setprio(0);
    if (t + 2 < NT) {
      WAITN();                           // t+1 ready, t+2 still flying
    } else {
      asm volatile("s_waitcnt vmcnt(0)" ::: "memory");
    }
    __builtin_amdgcn_sched_barrier(0);
    __builtin_amdgcn_s_barrier();
  }
#undef STG
#undef WAITN

  if constexpr (MODE == 0) {
    int wcb = bn + wc * 64;   // wave's 64-col window = one head
    __bf16* qb = (__bf16*)C0;
    if (wcb < 2048) {
#pragma unroll
      for (int mf = 0; mf < MF; mf++)
#pragma unroll
        for (int r = 0; r < 4; r++) {
          int row = bm + wr * (MF * 16) + mf * 16 + 4 * lk + r;
          int sidx = row & 2047;
#pragma unroll
          for (int nfl = 0; nfl < 2; nfl++) {
            int d = nfl * 16 + lrow;
            float c = ct[sidx * 32 + d], sn = st[sidx * 32 + d];
            float a = acc[mf][nfl][r], b2 = acc[mf][nfl + 2][r];
            qb[(size_t)row * 2048 + wcb + d] = (__bf16)((a * c - b2 * sn) * QSCALE);
            qb[(size_t)row * 2048 + wcb + d + 32] = (__bf16)((b2 * c + a * sn) * QSCALE);
          }
        }
    } else if (wcb < 2560) {
      int cb = wcb - 2048;
#pragma unroll
      for (int mf = 0; mf < MF; mf++)
#pragma unroll
        for (int r = 0; r < 4; r++) {
          int row = bm + wr * (MF * 16) + mf * 16 + 4 * lk + r;
          int sidx = row & 2047;
#pragma unroll
          for (int nfl = 0; nfl < 2; nfl++) {
            int d = nfl * 16 + lrow;
            float c = ct[sidx * 32 + d], sn = st[sidx * 32 + d];
            float a = acc[mf][nfl][r], b2 = acc[mf][nfl + 2][r];
            kb[(size_t)row * 512 + cb + d] = (__bf16)(a * c - b2 * sn);
            kb[(size_t)row * 512 + cb + d + 32] = (__bf16)(b2 * c + a * sn);
          }
        }
    } else {
      int hkk = (wcb - 2560) >> 6;
#pragma unroll
      for (int mf = 0; mf < MF; mf++)
#pragma unroll
        for (int nf = 0; nf < NF; nf++)
#pragma unroll
          for (int r = 0; r < 4; r++) {
            int row = bm + wr * (MF * 16) + mf * 16 + 4 * lk + r;
            int dd = nf * 16 + lrow;
            int bb = row >> 11, s = row & 2047;
            vt[(size_t)(((bb << 3) + hkk) * 64 + dd) * 2048 + s] = (__bf16)acc[mf][nf][r];
          }
    }
  } else {
    float* C = (float*)C0;
#pragma unroll
    for (int mf = 0; mf < MF; mf++)
#pragma unroll
      for (int nf = 0; nf < NF; nf++)
#pragma unroll
        for (int r = 0; r < 4; r++) {
          int row = bm + wr * (MF * 16) + mf * 16 + 4 * lk + r;
          int col = bn + wc * 64 + nf * 16 + lrow;
          C[(size_t)row * 2048 + col] = acc[mf][nf][r];
        }
  }
}

// ---------------- WO GEMM (round-2 measured-best): 3-deep A, upfront reads, swizzle ----
template <int BN, int NW, int WPN, int MODE>
__global__ __launch_bounds__(NW * 64, NW / 4) void k_gemm3d(const __bf16* __restrict__ A,
                                                            const __bf16* __restrict__ BT,
                                                            void* __restrict__ C0,
                                                            int K, int NBN) {
  constexpr int WPM = NW / WPN;
  constexpr int MF = 256 / WPM / 16;
  constexpr int NF = BN / WPN / 16;
  constexpr int MH = MF / 2;
  constexpr int CHA = 256 * 8;
  constexpr int CHB = BN * 8;
  constexpr int PA = CHA / (NW * 64);
  constexpr int RA = CHA - PA * NW * 64;
  constexpr int PB = CHB / (NW * 64);
  static_assert(CHB % (NW * 64) == 0, "B chunks must tile threads");
  static_assert(RA % 64 == 0, "A remainder must be wave-aligned");
  static_assert(NF == 4, "wave owns a 64-col window");
  constexpr int LB = PB;
  constexpr int LA0 = PA + (RA > 0 ? 1 : 0);
  constexpr int LA1 = PA;
  constexpr int NS0 = 2 * LA0 + LB, NS1 = 2 * LA1 + LB;
  constexpr int NM0 = LA0 + LB, NM1 = LA1 + LB;
  __shared__ __align__(16) __bf16 lA[3][256 * 64];
  __shared__ __align__(16) __bf16 lB[2][BN * 64];
  int bid = blockIdx.x;
  int lg = (bid & 7) * ((int)gridDim.x >> 3) + (bid >> 3);
  int bm = (lg / NBN) << 8;
  int bn = (lg % NBN) * BN;
  int tid = threadIdx.x, l = tid & 63, w = tid >> 6;
  int wr = w / WPN, wc = w % WPN;
  int lrow = l & 15, lk = l >> 4;
  int NT = K >> 6;
  f32x4 acc[MF][NF] = {};

#define STGA(T, BUF)                                                          \
  do {                                                                        \
    int k0_ = (T) << 6;                                                       \
    _Pragma("unroll") for (int i_ = 0; i_ < PA; i_++) {                       \
      int ch_ = i_ * (NW * 64) + tid;                                         \
      int r_ = ch_ >> 3, c_ = ch_ & 7;                                        \
      GL16(A + (size_t)(bm + r_) * K + k0_ + ((c_ ^ (r_ & 7)) << 3),          \
           &lA[BUF][(i_ * (NW * 64) + (w << 6)) * 8]);                        \
    }                                                                         \
    if constexpr (RA > 0) {                                                   \
      if (tid < RA) {                                                         \
        int ch_ = PA * (NW * 64) + tid;                                       \
        int r_ = ch_ >> 3, c_ = ch_ & 7;                                      \
        GL16(A + (size_t)(bm + r_) * K + k0_ + ((c_ ^ (r_ & 7)) << 3),        \
             &lA[BUF][(PA * (NW * 64) + (w << 6)) * 8]);                      \
      }                                                                       \
    }                                                                         \
  } while (0)

#define STGB(T, BUF)                                                          \
  do {                                                                        \
    int k0_ = (T) << 6;                                                       \
    _Pragma("unroll") for (int i_ = 0; i_ < PB; i_++) {                       \
      int ch_ = i_ * (NW * 64) + tid;                                         \
      int r_ = ch_ >> 3, c_ = ch_ & 7;                                        \
      GL16(BT + (size_t)(bn + r_) * K + k0_ + ((c_ ^ (r_ & 7)) << 3),         \
           &lB[BUF][(i_ * (NW * 64) + (w << 6)) * 8]);                        \
    }                                                                         \
  } while (0)

#define WAIT_STEADY()                                                         \
  do {                                                                        \
    if constexpr (RA > 0) {                                                   \
      if (w < (RA >> 6))                                                      \
        asm volatile("s_waitcnt vmcnt(%0)" ::"i"(NS0) : "memory");            \
      else                                                                    \
        asm volatile("s_waitcnt vmcnt(%0)" ::"i"(NS1) : "memory");            \
    } else {                                                                  \
      asm volatile("s_waitcnt vmcnt(%0)" ::"i"(NS1) : "memory");              \
    }                                                                         \
  } while (0)

#define WAIT_MID()                                                            \
  do {                                                                        \
    if constexpr (RA > 0) {                                                   \
      if (w < (RA >> 6))                                                      \
        asm volatile("s_waitcnt vmcnt(%0)" ::"i"(NM0) : "memory");            \
      else                                                                    \
        asm volatile("s_waitcnt vmcnt(%0)" ::"i"(NM1) : "memory");            \
    } else {                                                                  \
      asm volatile("s_waitcnt vmcnt(%0)" ::"i"(NM1) : "memory");              \
    }                                                                         \
  } while (0)

  STGB(0, 0); STGA(0, 0);
  STGB(1, 1); STGA(1, 1);
  STGA(2, 2);
  WAIT_STEADY();
  __builtin_amdgcn_sched_barrier(0);
  __builtin_amdgcn_s_barrier();

  int a0 = 0;
  for (int t = 0; t < NT; t++) {
    const char* bA = (const char*)lA[a0];
    const char* bB = (const char*)lB[t & 1];
    bf16x8 bfr[NF][2], af0[MH][2], af1[MH][2];
#pragma unroll
    for (int nf = 0; nf < NF; nf++) {
      int row = wc * (NF * 16) + nf * 16 + lrow;
#pragma unroll
      for (int kc = 0; kc < 2; kc++)
        bfr[nf][kc] = *(const bf16x8*)(bB + row * 128 +
                                       ((kc * 64 + 16 * lk) ^ ((row & 7) << 4)));
    }
#pragma unroll
    for (int mf = 0; mf < MH; mf++) {
      int row = wr * (MF * 16) + mf * 16 + lrow;
#pragma unroll
      for (int kc = 0; kc < 2; kc++)
        af0[mf][kc] = *(const bf16x8*)(bA + row * 128 +
                                       ((kc * 64 + 16 * lk) ^ ((row & 7) << 4)));
    }
#pragma unroll
    for (int mf = 0; mf < MH; mf++) {
      int row = wr * (MF * 16) + (MH + mf) * 16 + lrow;
#pragma unroll
      for (int kc = 0; kc < 2; kc++)
        af1[mf][kc] = *(const bf16x8*)(bA + row * 128 +
                                       ((kc * 64 + 16 * lk) ^ ((row & 7) << 4)));
    }
    __builtin_amdgcn_s_setprio(1);
#pragma unroll
    for (int kc = 0; kc < 2; kc++)
#pragma unroll
      for (int mf = 0; mf < MH; mf++)
#pragma unroll
        for (int nf = 0; nf < NF; nf++)
          acc[mf][nf] = __builtin_amdgcn_mfma_f32_16x16x32_bf16(af0[mf][kc], bfr[nf][kc],
                                                                acc[mf][nf], 0, 0, 0);
    __builtin_amdgcn_s_setprio(0);
    asm volatile("s_waitcnt lgkmcnt(0)" ::: "memory");
    __builtin_amdgcn_sched_barrier(0);
    __builtin_amdgcn_s_barrier();
    if (t + 2 < NT) STGB(t + 2, t & 1);
    if (t + 3 < NT) STGA(t + 3, a0);
    __builtin_amdgcn_s_setprio(1);
#pragma unroll
    for (int kc = 0; kc < 2; kc++)
#pragma unroll
      for (int mf = 0; mf < MH; mf++)
#pragma unroll
        for (int nf = 0; nf < NF; nf++)
          acc[MH + mf][nf] = __builtin_amdgcn_mfma_f32_16x16x32_bf16(
              af1[mf][kc], bfr[nf][kc], acc[MH + mf][nf], 0, 0, 0);
    __builtin_amdgcn_s_setprio(0);
    if (t + 3 < NT) {
      WAIT_STEADY();
    } else if (t + 2 < NT) {
      WAIT_MID();
    } else if (t + 1 < NT) {
      asm volatile("s_waitcnt vmcnt(0)" ::: "memory");
    }
    __builtin_amdgcn_sched_barrier(0);
    __builtin_amdgcn_s_barrier();
    a0 = (a0 == 2) ? 0 : a0 + 1;
  }
#undef STGA
#undef STGB
#undef WAIT_STEADY
#undef WAIT_MID

  float* C = (float*)C0;
#pragma unroll
  for (int mf = 0; mf < MF; mf++)
#pragma unroll
    for (int nf = 0; nf < NF; nf++)
#pragma unroll
      for (int r = 0; r < 4; r++) {
        int row = bm + wr * (MF * 16) + mf * 16 + 4 * lk + r;
        int col = bn + wc * 64 + nf * 16 + lrow;
        C[(size_t)row * 2048 + col] = acc[mf][nf][r];
      }
}

// ---------------- causal GQA flash attention v4c ----------------
// v4 structure (QBLK=32, grid 1024, descending-c dispatch — r5 measured-best),
// launch_bounds(256,3), setprio on MFMA clusters.
__global__ __launch_bounds__(256, 3) void k_attn(const __bf16* __restrict__ Q,
                                                 const __bf16* __restrict__ Kb,
                                                 const __bf16* __restrict__ VT,
                                                 __bf16* __restrict__ O) {
  __shared__ __align__(16) __bf16 lK[2][64 * 64];
  __shared__ __align__(16) __bf16 lV[2][64 * 64];
  int bid = blockIdx.x;            // 1024
  int c = 63 - (bid >> 4);         // q-chunk of 32 rows, most work first
  int hk = bid & 7;
  int b = (bid >> 3) & 1;
  int tid = threadIdx.x, l = tid & 63, w = tid >> 6;
  int h = hk * 4 + w;
  int lrow = l & 15, lk = l >> 4;
  int sw = (lrow & 7) << 4;
  int tl = c >> 1;                 // last kv tile index

#define STAGE(BUF, T)                                                                     \
  do {                                                                                    \
    int kv0_ = (T) * 64;                                                                  \
    _Pragma("unroll") for (int i_ = 0; i_ < 2; i_++) {                                    \
      int cb_ = i_ * 256 + w * 64;                                                        \
      int chunk_ = cb_ + l;                                                               \
      int row_ = chunk_ >> 3, cc_ = chunk_ & 7;                                           \
      GL16(Kb + (size_t)(b * 2048 + kv0_ + row_) * 512 + hk * 64 +                        \
               ((cc_ ^ (row_ & 7)) << 3),                                                 \
           &lK[BUF][cb_ * 8]);                                                            \
      GL16(VT + (size_t)((b * 8 + hk) * 64 + row_) * 2048 + kv0_ +                        \
               ((cc_ ^ (row_ & 7)) << 3),                                                 \
           &lV[BUF][cb_ * 8]);                                                            \
    }                                                                                     \
  } while (0)

  // Q fragments: 2 q-frags x 2 k-chunks, live in registers for the whole pass
  bf16x8 aq[2][2];
#pragma unroll
  for (int qf = 0; qf < 2; qf++) {
    int qrow = c * 32 + qf * 16 + lrow;
    const __bf16* qp = Q + (size_t)(b * 2048 + qrow) * 2048 + h * 64 + lk * 8;
    aq[qf][0] = *(const bf16x8*)qp;
    aq[qf][1] = *(const bf16x8*)(qp + 32);
  }
  f32x4 o[2][4] = {};
  float lp[2] = {0.f, 0.f};
  STAGE(0, 0);
  for (int t = 0, buf = 0; t <= tl; t++, buf ^= 1) {
    asm volatile("s_waitcnt vmcnt(0)" ::: "memory");
    __syncthreads();
    if (t < tl) STAGE(buf ^ 1, t + 1);
    const char* K_ = (const char*)lK[buf];
    const char* V_ = (const char*)lV[buf];
    // swapped QK^T: s4[qf][nf][r] = P^T[kv = nf*16+4*lk+r][q = lrow] (tile-local)
    f32x4 s4[2][4];
    __builtin_amdgcn_s_setprio(1);
#pragma unroll
    for (int nf = 0; nf < 4; nf++) {
      const char* kr = K_ + (nf * 16 + lrow) * 128;
      bf16x8 bk0 = *(const bf16x8*)(kr + ((16 * lk) ^ sw));
      bf16x8 bk1 = *(const bf16x8*)(kr + ((64 + 16 * lk) ^ sw));
#pragma unroll
      for (int qf = 0; qf < 2; qf++) {
        f32x4 z = {};
        z = __builtin_amdgcn_mfma_f32_16x16x32_bf16(bk0, aq[qf][0], z, 0, 0, 0);
        z = __builtin_amdgcn_mfma_f32_16x16x32_bf16(bk1, aq[qf][1], z, 0, 0, 0);
        s4[qf][nf] = z;
      }
    }
    __builtin_amdgcn_s_setprio(0);
    if (t == tl) {
      int qo = (c & 1) * 32;
#pragma unroll
      for (int qf = 0; qf < 2; qf++) {
        int qoff = qo + qf * 16 + lrow;
#pragma unroll
        for (int nf = 0; nf < 4; nf++)
#pragma unroll
          for (int r = 0; r < 4; r++)
            if (nf * 16 + 4 * lk + r > qoff) s4[qf][nf][r] = -1e30f;
      }
    }
    // no-max softmax: p = 2^s (s pre-scaled by log2e/8; bounded), in-lane partial sums
#pragma unroll
    for (int qf = 0; qf < 2; qf++) {
      float ps = 0.f;
#pragma unroll
      for (int nf = 0; nf < 4; nf++)
#pragma unroll
        for (int r = 0; r < 4; r++) {
          float pv = ex2(s4[qf][nf][r]);
          s4[qf][nf][r] = pv;
          ps += pv;
        }
      lp[qf] += ps;
    }
    // PV: o^T[d][q] += V^T * P^T, nf-tiles paired {np, np+2} into one 16x16x32 MFMA
    __builtin_amdgcn_s_setprio(1);
#pragma unroll
    for (int np = 0; np < 2; np++) {
      bf16x8 pb[2];
#pragma unroll
      for (int qf = 0; qf < 2; qf++) {
        uint4 t4;
        t4.x = pkbf(s4[qf][np][0], s4[qf][np][1]);
        t4.y = pkbf(s4[qf][np][2], s4[qf][np][3]);
        t4.z = pkbf(s4[qf][np + 2][0], s4[qf][np + 2][1]);
        t4.w = pkbf(s4[qf][np + 2][2], s4[qf][np + 2][3]);
        pb[qf] = __builtin_bit_cast(bf16x8, t4);
      }
#pragma unroll
      for (int dn = 0; dn < 4; dn++) {
        const char* vr = V_ + (dn * 16 + lrow) * 128;
        uint2 a0 = *(const uint2*)(vr + ((np * 32 + 8 * lk) ^ sw));
        uint2 a1 = *(const uint2*)(vr + (((np + 2) * 32 + 8 * lk) ^ sw));
        uint4 av;
        av.x = a0.x; av.y = a0.y; av.z = a1.x; av.w = a1.y;
        bf16x8 va = __builtin_bit_cast(bf16x8, av);
#pragma unroll
        for (int qf = 0; qf < 2; qf++)
          o[qf][dn] = __builtin_amdgcn_mfma_f32_16x16x32_bf16(va, pb[qf], o[qf][dn], 0, 0, 0);
      }
    }
    __builtin_amdgcn_s_setprio(0);
  }
  // epilogue: reduce lp across the 4 lk-lanes of each q-row, normalize, store b64 packs
#pragma unroll
  for (int qf = 0; qf < 2; qf++) {
    float s = lp[qf];
    s += __shfl_xor(s, 16);
    s += __shfl_xor(s, 32);
    float inv = 1.f / s;
    int qrow = c * 32 + qf * 16 + lrow;
    __bf16* op = O + (size_t)(b * 2048 + qrow) * 2048 + h * 64 + 4 * lk;
#pragma unroll
    for (int dn = 0; dn < 4; dn++) {
      bf16x4 stv;
#pragma unroll
      for (int r = 0; r < 4; r++) stv[r] = (__bf16)(o[qf][dn][r] * inv);
      *(bf16x4*)(op + dn * 16) = stv;
    }
  }
#undef STAGE
}

extern "C" void kernel_launch(void* const* d_in, const int* in_sizes, int n_in,
                              void* d_out, int out_size, void* d_ws, size_t ws_size,
                              hipStream_t stream) {
  const float* x = (const float*)d_in[0];
  const float* wq = (const float*)d_in[1];
  const float* wk = (const float*)d_in[2];
  const float* wv = (const float*)d_in[3];
  const float* wo = (const float*)d_in[4];
  char* ws = (char*)d_ws;
  __bf16* xb    = (__bf16*)(ws + 0);          // 16,777,216
  __bf16* wqkvT = (__bf16*)(ws + 16777216);   // 12,582,912  [3072][2048]
  __bf16* woT   = (__bf16*)(ws + 29360128);   //  8,388,608
  __bf16* qb    = (__bf16*)(ws + 37748736);   // 16,777,216
  __bf16* kb    = (__bf16*)(ws + 54525952);   //  4,194,304
  __bf16* vt    = (__bf16*)(ws + 58720256);   //  4,194,304
  __bf16* ob    = (__bf16*)(ws + 62914560);   // 16,777,216
  float*  ct    = (float*)(ws + 79691776);    //    262,144
  float*  st    = (float*)(ws + 79953920);    //    262,144
  float* out = (float*)d_out;

  // one fused prep launch: cvt + wq/wk/wv/wo transpose-convert + rope table
  k_prep<<<14592, 256, 0, stream>>>(x, xb, wq, wk, wv, wo, wqkvT, woT, ct, st);
  // QKV: round-1 structure, grid 16x16 = 256 blocks -> every CU gets one block.
  k_gemm256<192, 12, 3, 0><<<256, 768, 0, stream>>>(xb, wqkvT, qb, kb, vt, ct, st, 2048, 16);
  // attn: descending-c dispatch (r5 measured-best).
  k_attn<<<1024, 256, 0, stream>>>(qb, kb, vt, ob);
  // WO: round-2 structure (3-deep A pipeline + XCD swizzle), measured faster for MODE 1.
  k_gemm3d<128, 8, 2, 1><<<256, 512, 0, stream>>>(ob, woT, out, 2048, 16);
}